// Round 2
// baseline (333.523 us; speedup 1.0000x reference)
//
#include <hip/hip_runtime.h>

typedef __attribute__((ext_vector_type(8))) short bf16x8;
typedef __attribute__((ext_vector_type(8))) _Float16 f16x8;
typedef __attribute__((ext_vector_type(4))) _Float16 f16x4;
typedef __attribute__((ext_vector_type(4))) float f32x4;

__device__ __forceinline__ short f2bf(float x){
  unsigned u = __float_as_uint(x);
  u += 0x7fffu + ((u >> 16) & 1u);
  return (short)(u >> 16);
}
__device__ __forceinline__ float bf2f(short b){
  return __uint_as_float(((unsigned)(unsigned short)b) << 16);
}

#define DDIM 128
#define NADDR 4096
#define VDIM 512
#define NT 32

__global__ __launch_bounds__(256, 2)
void soft_addr_kernel(const float* __restrict__ sel,
                      const float* __restrict__ bank,
                      const float* __restrict__ addr,
                      float* __restrict__ out)
{
  // sK: address_space tile [32 n][128 d] fp16, pad->136 (272B rows: 16B-aligned b128 reads)
  // sV: param_bank tile   [32 n][128 v] bf16, pad->132
  // sP: exp(S) tile       [128 m][32 n] bf16, pad->40 (80B rows: aligned b128 A-frag reads)
  __shared__ __align__(16) _Float16 sK[32][136];
  __shared__ __align__(16) short sV[32][132];
  __shared__ __align__(16) short sP[128][40];
  __shared__ float sL[128];

  const int tid  = threadIdx.x;
  const int wave = tid >> 6;
  const int lane = tid & 63;
  const int quad = lane >> 4;
  const int l16  = lane & 15;

  const int bid  = blockIdx.x;
  const int vblk = bid & 3;          // which 128-wide slice of V
  const int mblk = bid >> 2;         // which 128-row tile of M
  const int m0   = mblk * 128;
  const int v0   = vblk * 128;

  // per-wave O tile: 64x64 within the 128x128 (rows wm.., cols wn..)
  const int wm = (wave >> 1) * 64;
  const int wn = (wave & 1) * 64;

  // ---- Q fragments (A-operand layout, fp16), loop-invariant, in registers ----
  // wave computes S rows [32*wave, 32*wave+32)
  f16x8 aQ[2][4];
  #pragma unroll
  for (int mi = 0; mi < 2; ++mi){
    const float* q = sel + (size_t)(m0 + 32*wave + 16*mi + l16) * DDIM + quad*8;
    #pragma unroll
    for (int ks = 0; ks < 4; ++ks){
      float4 a = *(const float4*)(q + 32*ks);
      float4 b = *(const float4*)(q + 32*ks + 4);
      f16x8 f;
      f[0]=(_Float16)a.x; f[1]=(_Float16)a.y; f[2]=(_Float16)a.z; f[3]=(_Float16)a.w;
      f[4]=(_Float16)b.x; f[5]=(_Float16)b.y; f[6]=(_Float16)b.z; f[7]=(_Float16)b.w;
      aQ[mi][ks] = f;
    }
  }

  f32x4 oAcc[4][4];
  const f32x4 fz = {0.f,0.f,0.f,0.f};
  #pragma unroll
  for (int i=0;i<4;++i)
    #pragma unroll
    for (int j=0;j<4;++j) oAcc[i][j]=fz;
  float lacc[2][4] = {{0.f,0.f,0.f,0.f},{0.f,0.f,0.f,0.f}};

  const int sr = tid >> 3;          // staging row 0..31
  const int sc = (tid & 7) * 16;    // staging col base

  for (int nt = 0; nt < NADDR/NT; ++nt){
    const int n0 = nt * NT;
    __syncthreads();   // previous iteration's LDS reads complete

    // ---- stage K tile (32 x 128 fp32 -> fp16) ----
    {
      const float* src = addr + (size_t)(n0 + sr)*DDIM + sc;
      #pragma unroll
      for (int i=0;i<4;++i){
        float4 qv = *(const float4*)(src + 4*i);
        f16x4 h;
        h[0]=(_Float16)qv.x; h[1]=(_Float16)qv.y; h[2]=(_Float16)qv.z; h[3]=(_Float16)qv.w;
        *(f16x4*)&sK[sr][sc + 4*i] = h;
      }
    }
    // ---- stage V tile (32 x 128 fp32 -> bf16) ----
    {
      const float* src = bank + (size_t)(n0 + sr)*VDIM + v0 + sc;
      #pragma unroll
      for (int i=0;i<4;++i){
        float4 qv = *(const float4*)(src + 4*i);
        short4 s4 = make_short4(f2bf(qv.x),f2bf(qv.y),f2bf(qv.z),f2bf(qv.w));
        *(short4*)&sV[sr][sc + 4*i] = s4;
      }
    }
    __syncthreads();   // staged tiles visible

    // ---- S = Q . K^T  (wave: 32 rows x 32 cols, K=128, fp16 inputs) ----
    f32x4 sAcc[2][2];
    sAcc[0][0]=fz; sAcc[0][1]=fz; sAcc[1][0]=fz; sAcc[1][1]=fz;
    #pragma unroll
    for (int ks=0; ks<4; ++ks){
      f16x8 bK[2];
      #pragma unroll
      for (int ni=0; ni<2; ++ni)
        bK[ni] = *(const f16x8*)&sK[16*ni + l16][32*ks + quad*8];
      #pragma unroll
      for (int mi=0; mi<2; ++mi)
        #pragma unroll
        for (int ni=0; ni<2; ++ni)
          sAcc[mi][ni] = __builtin_amdgcn_mfma_f32_16x16x32_f16(
              aQ[mi][ks], bK[ni], sAcc[mi][ni], 0,0,0);
    }

    // ---- P = exp(S) (unnormalized), bf16-round, stash to LDS, row sums ----
    // lacc accumulates the ROUNDED p so numerator/denominator are consistent.
    #pragma unroll
    for (int mi=0; mi<2; ++mi)
      #pragma unroll
      for (int ni=0; ni<2; ++ni)
        #pragma unroll
        for (int r=0; r<4; ++r){
          float p = __expf(sAcc[mi][ni][r]);
          short pq = f2bf(p);
          lacc[mi][r] += bf2f(pq);
          sP[32*wave + 16*mi + 4*quad + r][16*ni + l16] = pq;
        }
    __syncthreads();   // sP visible

    // ---- O += P . V  (wave: 64x64 tile, K=32, bf16) ----
    bf16x8 aP[4];
    #pragma unroll
    for (int i=0;i<4;++i)
      aP[i] = *(const bf16x8*)&sP[wm + 16*i + l16][quad*8];
    bf16x8 bV[4];
    #pragma unroll
    for (int jx=0;jx<4;++jx){
      bf16x8 f;
      #pragma unroll
      for (int j=0;j<8;++j) f[j] = sV[quad*8 + j][wn + 16*jx + l16];
      bV[jx] = f;
    }
    #pragma unroll
    for (int i=0;i<4;++i)
      #pragma unroll
      for (int jx=0;jx<4;++jx)
        oAcc[i][jx] = __builtin_amdgcn_mfma_f32_16x16x32_bf16(
            aP[i], bV[jx], oAcc[i][jx], 0,0,0);
  }

  // ---- denominator: reduce lacc across the 16 lanes of each quad ----
  #pragma unroll
  for (int mi=0; mi<2; ++mi)
    #pragma unroll
    for (int r=0;r<4;++r){
      float s = lacc[mi][r];
      s += __shfl_xor(s, 1);
      s += __shfl_xor(s, 2);
      s += __shfl_xor(s, 4);
      s += __shfl_xor(s, 8);
      if (l16 == 0) sL[32*wave + 16*mi + 4*quad + r] = s;
    }
  __syncthreads();

  // ---- epilogue: divide + store ----
  #pragma unroll
  for (int i=0;i<4;++i){
    #pragma unroll
    for (int r=0;r<4;++r){
      int rl = wm + 16*i + 4*quad + r;
      float inv = 1.0f / sL[rl];
      float* op = out + (size_t)(m0 + rl)*VDIM + v0 + wn;
      #pragma unroll
      for (int jx=0;jx<4;++jx)
        op[16*jx + l16] = oAcc[i][jx][r] * inv;
    }
  }
}

extern "C" void kernel_launch(void* const* d_in, const int* in_sizes, int n_in,
                              void* d_out, int out_size, void* d_ws, size_t ws_size,
                              hipStream_t stream) {
  const float* sel  = (const float*)d_in[0];   // [8,2048,128]
  const float* bank = (const float*)d_in[1];   // [4096,512]
  const float* addr = (const float*)d_in[2];   // [4096,128]
  float* out = (float*)d_out;                  // [8,2048,512]
  dim3 grid(512), block(256);
  hipLaunchKernelGGL(soft_addr_kernel, grid, block, 0, stream, sel, bank, addr, out);
}

// Round 4
// 255.634 us; speedup vs baseline: 1.3047x; 1.3047x over previous
//
#include <hip/hip_runtime.h>

typedef __attribute__((ext_vector_type(8))) short bf16x8;
typedef __attribute__((ext_vector_type(8))) _Float16 f16x8;
typedef __attribute__((ext_vector_type(2))) __fp16 fp16v2;
typedef __attribute__((ext_vector_type(4))) float f32x4;

#define DDIM 128
#define NADDR 4096
#define VDIM 512
#define NT 32
#define LOG2E 1.44269504088896340736f

// pack hi16(lo), hi16(hi) -> one dword: low short = bf16-trunc(lo), high = bf16-trunc(hi)
__device__ __forceinline__ unsigned pkhi(float hi, float lo){
  return __builtin_amdgcn_perm(__float_as_uint(hi), __float_as_uint(lo), 0x07060302u);
}

__global__ __launch_bounds__(512, 4)
void soft_addr_kernel(const float* __restrict__ sel,
                      const float* __restrict__ bank,
                      const float* __restrict__ addr,
                      float* __restrict__ out)
{
  // sK : K tile  [32 n][128 d] fp16, stride 136 (16B-aligned rows, padded)
  // sVt: V tile TRANSPOSED [128 v][32 n] bf16, stride 40 -> bV frags are b128 reads
  // sP : exp(S)  [128 m][32 n] bf16, stride 40 -> aP frags are b128 reads
  __shared__ __align__(16) _Float16 sK[32][136];
  __shared__ __align__(16) short sVt[128][40];
  __shared__ __align__(16) short sP[128][40];
  __shared__ float sL[2][128];

  const int tid  = threadIdx.x;
  const int wave = tid >> 6;
  const int lane = tid & 63;
  const int quad = lane >> 4;
  const int l16  = lane & 15;

  const int bid  = blockIdx.x;
  const int vblk = bid & 3;          // 128-wide V slice
  const int mblk = bid >> 2;         // 128-row M tile
  const int m0 = mblk * 128, v0 = vblk * 128;

  const int swr = (wave >> 1) * 32;  // S-phase row base (also PV row base)
  const int swc = (wave & 1) * 16;   // S-phase col base (within 32-n tile)
  const int wn  = (wave & 1) * 64;   // PV col base (within 128-v slice)

  // ---- Q fragments (A layout), pre-scaled by log2(e), fp16, loop-invariant ----
  f16x8 aQ[2][4];
  #pragma unroll
  for (int mi = 0; mi < 2; ++mi){
    const float* q = sel + (size_t)(m0 + swr + 16*mi + l16) * DDIM + quad*8;
    #pragma unroll
    for (int ks = 0; ks < 4; ++ks){
      float4 a = *(const float4*)(q + 32*ks);
      float4 b = *(const float4*)(q + 32*ks + 4);
      f16x8 f;
      f[0]=(_Float16)(a.x*LOG2E); f[1]=(_Float16)(a.y*LOG2E);
      f[2]=(_Float16)(a.z*LOG2E); f[3]=(_Float16)(a.w*LOG2E);
      f[4]=(_Float16)(b.x*LOG2E); f[5]=(_Float16)(b.y*LOG2E);
      f[6]=(_Float16)(b.z*LOG2E); f[7]=(_Float16)(b.w*LOG2E);
      aQ[mi][ks] = f;
    }
  }

  f32x4 oAcc[2][4];
  const f32x4 fz = {0.f,0.f,0.f,0.f};
  #pragma unroll
  for (int i=0;i<2;++i)
    #pragma unroll
    for (int j=0;j<4;++j) oAcc[i][j]=fz;
  float lacc[2][4] = {{0.f,0.f,0.f,0.f},{0.f,0.f,0.f,0.f}};

  // staging maps
  const int ksr = tid >> 4;          // K: row 0..31
  const int ksc = (tid & 15) * 8;    // K: col base (8 floats)
  const int vc  = tid & 127;         // V: column 0..127 (coalesced across wave)
  const int vnb = (tid >> 7) * 8;    // V: n base {0,8,16,24}

  for (int nt = 0; nt < NADDR/NT; ++nt){
    const int n0 = nt * NT;
    __syncthreads();   // prior iteration's LDS reads complete

    // ---- stage K tile (fp32 -> fp16 via pkrtz, one b128 write) ----
    {
      const float* src = addr + (size_t)(n0 + ksr)*DDIM + ksc;
      float4 a = *(const float4*)(src);
      float4 b = *(const float4*)(src + 4);
      union { f16x8 v; fp16v2 h[4]; } u;
      u.h[0] = __builtin_amdgcn_cvt_pkrtz(a.x, a.y);
      u.h[1] = __builtin_amdgcn_cvt_pkrtz(a.z, a.w);
      u.h[2] = __builtin_amdgcn_cvt_pkrtz(b.x, b.y);
      u.h[3] = __builtin_amdgcn_cvt_pkrtz(b.z, b.w);
      *(f16x8*)&sK[ksr][ksc] = u.v;
    }
    // ---- stage V tile transposed (column-group read, perm-pack, one b128 write) ----
    {
      const float* src = bank + (size_t)(n0 + vnb)*VDIM + v0 + vc;
      float v[8];
      #pragma unroll
      for (int j=0;j<8;++j) v[j] = src[(size_t)j*VDIM];
      uint4 pk;
      pk.x = pkhi(v[1], v[0]);
      pk.y = pkhi(v[3], v[2]);
      pk.z = pkhi(v[5], v[4]);
      pk.w = pkhi(v[7], v[6]);
      *(uint4*)&sVt[vc][vnb] = pk;
    }
    __syncthreads();   // staged tiles visible

    // ---- S = Q.K^T : wave computes 32 rows x 16 cols, K=128 (fp16) ----
    f32x4 sAcc[2];
    sAcc[0]=fz; sAcc[1]=fz;
    #pragma unroll
    for (int ks=0; ks<4; ++ks){
      f16x8 bK = *(const f16x8*)&sK[swc + l16][32*ks + quad*8];
      sAcc[0] = __builtin_amdgcn_mfma_f32_16x16x32_f16(aQ[0][ks], bK, sAcc[0], 0,0,0);
      sAcc[1] = __builtin_amdgcn_mfma_f32_16x16x32_f16(aQ[1][ks], bK, sAcc[1], 0,0,0);
    }

    // ---- P = 2^S (unnormalized), truncate to bf16, stash + partial row sums ----
    #pragma unroll
    for (int mi=0; mi<2; ++mi)
      #pragma unroll
      for (int r=0; r<4; ++r){
        float p = __builtin_amdgcn_exp2f(sAcc[mi][r]);
        unsigned u = __float_as_uint(p);
        lacc[mi][r] += __uint_as_float(u & 0xffff0000u);
        sP[swr + 16*mi + 4*quad + r][swc + l16] = (short)(u >> 16);
      }
    __syncthreads();   // sP visible

    // ---- O += P.V : wave computes 32 rows x 64 cols, K=32 (bf16) ----
    bf16x8 aP[2];
    #pragma unroll
    for (int i=0;i<2;++i)
      aP[i] = *(const bf16x8*)&sP[swr + 16*i + l16][quad*8];
    bf16x8 bV[4];
    #pragma unroll
    for (int jx=0;jx<4;++jx)
      bV[jx] = *(const bf16x8*)&sVt[wn + 16*jx + l16][quad*8];
    #pragma unroll
    for (int i=0;i<2;++i)
      #pragma unroll
      for (int jx=0;jx<4;++jx)
        oAcc[i][jx] = __builtin_amdgcn_mfma_f32_16x16x32_bf16(
            aP[i], bV[jx], oAcc[i][jx], 0,0,0);
  }

  // ---- partial denominators (this wave covered 16 of 32 cols per n-tile) ----
  #pragma unroll
  for (int mi=0; mi<2; ++mi)
    #pragma unroll
    for (int r=0;r<4;++r){
      float s = lacc[mi][r];
      s += __shfl_xor(s, 1);
      s += __shfl_xor(s, 2);
      s += __shfl_xor(s, 4);
      s += __shfl_xor(s, 8);
      if (l16 == 0) sL[wave & 1][swr + 16*mi + 4*quad + r] = s;
    }
  __syncthreads();

  // ---- epilogue: divide + store ----
  #pragma unroll
  for (int i=0;i<2;++i){
    #pragma unroll
    for (int r=0;r<4;++r){
      int row = swr + 16*i + 4*quad + r;
      float inv = 1.0f / (sL[0][row] + sL[1][row]);
      float* op = out + (size_t)(m0 + row)*VDIM + v0 + wn;
      #pragma unroll
      for (int jx=0;jx<4;++jx)
        op[16*jx + l16] = oAcc[i][jx][r] * inv;
    }
  }
}

extern "C" void kernel_launch(void* const* d_in, const int* in_sizes, int n_in,
                              void* d_out, int out_size, void* d_ws, size_t ws_size,
                              hipStream_t stream) {
  const float* sel  = (const float*)d_in[0];   // [8,2048,128]
  const float* bank = (const float*)d_in[1];   // [4096,512]
  const float* addr = (const float*)d_in[2];   // [4096,128]
  float* out = (float*)d_out;                  // [8,2048,512]
  dim3 grid(512), block(512);
  hipLaunchKernelGGL(soft_addr_kernel, grid, block, 0, stream, sel, bank, addr, out);
}